// Round 1
// baseline (1572.094 us; speedup 1.0000x reference)
//
#include <hip/hip_runtime.h>
#include <hip/hip_bf16.h>

// StructureMapper: B=8192, R=6, D=1024, H=256, TEMP=0.5, 5 sinkhorn iters
// Rows = B*R = 49152.  All GEMM dims are multiples of tile sizes -> no bounds checks.

typedef float f32x4 __attribute__((ext_vector_type(4)));
typedef short s16x8 __attribute__((ext_vector_type(8)));
typedef short s16x4 __attribute__((ext_vector_type(4)));

__device__ __forceinline__ unsigned short f2bf(float x) {
  unsigned int u = __float_as_uint(x);
  u += 0x7FFFu + ((u >> 16) & 1u);            // RTNE
  return (unsigned short)(u >> 16);
}
__device__ __forceinline__ float bf2f(unsigned short b) {
  return __uint_as_float(((unsigned int)b) << 16);
}

// ---------------------------------------------------------------------------
// Generic NT GEMM: C[m,n] = act( sum_k A[m,k]*W[n,k] + bias[n] )
// A: fp32 [M,K] global, split to bf16 hi/lo on the fly (SPLIT=true -> 3-pass
// error-compensated product; false -> plain bf16).
// W: pre-split bf16 hi/lo [N,K].
// Tile 128x128x64, 256 threads (4 waves, 2x2), mfma_f32_16x16x32_bf16.
// grid = (N/128, M/128): consecutive blocks share the A tile (L3 reuse).
// LDS uses byte ^= ((row&7)<<4) XOR swizzle (G4) on 16B chunks.
// ---------------------------------------------------------------------------
template<bool SPLIT, int ACT>   // ACT: 0 none, 1 gelu(tanh)
__global__ __launch_bounds__(256, 2)
void gemm_nt(const float* __restrict__ A,
             const short* __restrict__ Whi, const short* __restrict__ Wlo,
             const float* __restrict__ bias, float* __restrict__ C,
             int K, int N)
{
  constexpr int BM = 128, BN = 128, BK = 64;
  __shared__ __attribute__((aligned(16))) short sAhi[BM * BK];
  __shared__ __attribute__((aligned(16))) short sBhi[BN * BK];
  __shared__ __attribute__((aligned(16))) short sAlo[SPLIT ? BM * BK : 8];
  __shared__ __attribute__((aligned(16))) short sBlo[SPLIT ? BN * BK : 8];

  const int tid = threadIdx.x;
  const int n0 = blockIdx.x * BN;
  const int m0 = blockIdx.y * BM;
  const int lane = tid & 63, w = tid >> 6;
  const int wr = (w >> 1) * 64, wc = (w & 1) * 64;

  f32x4 acc[4][4] = {};

  for (int k0 = 0; k0 < K; k0 += BK) {
    __syncthreads();
    // ---- stage A: fp32 -> hi/lo bf16, swizzled LDS ----
#pragma unroll
    for (int it = 0; it < 8; ++it) {
      int f = it * 256 + tid;          // float4 id within 128x64 tile
      int r = f >> 4, q = f & 15;      // row, float4-within-row
      f32x4 v = *reinterpret_cast<const f32x4*>(A + (size_t)(m0 + r) * K + k0 + q * 4);
      s16x4 hi, lo;
#pragma unroll
      for (int j = 0; j < 4; ++j) {
        unsigned short h = f2bf(v[j]);
        hi[j] = (short)h;
        if (SPLIT) lo[j] = (short)f2bf(v[j] - bf2f(h));
      }
      int off = r * 64 + (((q >> 1) ^ (r & 7)) << 3) + ((q & 1) << 2);
      *reinterpret_cast<s16x4*>(&sAhi[off]) = hi;
      if (SPLIT) *reinterpret_cast<s16x4*>(&sAlo[off]) = lo;
    }
    // ---- stage B: pre-split bf16, swizzled LDS ----
#pragma unroll
    for (int it = 0; it < 4; ++it) {
      int c = it * 256 + tid;          // 16B-chunk id within 128x64 tile
      int r = c >> 3, ch = c & 7;
      size_t g = (size_t)(n0 + r) * K + k0 + ch * 8;
      int off = r * 64 + ((ch ^ (r & 7)) << 3);
      *reinterpret_cast<s16x8*>(&sBhi[off]) = *reinterpret_cast<const s16x8*>(Whi + g);
      if (SPLIT) *reinterpret_cast<s16x8*>(&sBlo[off]) = *reinterpret_cast<const s16x8*>(Wlo + g);
    }
    __syncthreads();
    // ---- MFMA ----
#pragma unroll
    for (int kc = 0; kc < 2; ++kc) {
      s16x8 ah[4], al[4];
#pragma unroll
      for (int mt = 0; mt < 4; ++mt) {
        int r = wr + mt * 16 + (lane & 15);
        int off = r * 64 + ((((kc << 2) + (lane >> 4)) ^ (r & 7)) << 3);
        ah[mt] = *reinterpret_cast<const s16x8*>(&sAhi[off]);
        if (SPLIT) al[mt] = *reinterpret_cast<const s16x8*>(&sAlo[off]);
      }
#pragma unroll
      for (int nt = 0; nt < 4; ++nt) {
        int r = wc + nt * 16 + (lane & 15);
        int off = r * 64 + ((((kc << 2) + (lane >> 4)) ^ (r & 7)) << 3);
        s16x8 bh = *reinterpret_cast<const s16x8*>(&sBhi[off]);
        s16x8 bl = {};
        if (SPLIT) bl = *reinterpret_cast<const s16x8*>(&sBlo[off]);
#pragma unroll
        for (int mt = 0; mt < 4; ++mt) {
          acc[mt][nt] = __builtin_amdgcn_mfma_f32_16x16x32_bf16(ah[mt], bh, acc[mt][nt], 0, 0, 0);
          if (SPLIT) {
            acc[mt][nt] = __builtin_amdgcn_mfma_f32_16x16x32_bf16(ah[mt], bl, acc[mt][nt], 0, 0, 0);
            acc[mt][nt] = __builtin_amdgcn_mfma_f32_16x16x32_bf16(al[mt], bh, acc[mt][nt], 0, 0, 0);
          }
        }
      }
    }
  }
  // ---- epilogue: C/D layout col=lane&15, row=(lane>>4)*4+j (m89-verified) ----
#pragma unroll
  for (int mt = 0; mt < 4; ++mt) {
#pragma unroll
    for (int nt = 0; nt < 4; ++nt) {
      int cc = n0 + wc + nt * 16 + (lane & 15);
      float bv = bias ? bias[cc] : 0.f;
#pragma unroll
      for (int j = 0; j < 4; ++j) {
        int rr = m0 + wr + mt * 16 + (lane >> 4) * 4 + j;
        float v = acc[mt][nt][j] + bv;
        if (ACT == 1) {
          float x3 = v * v * v;
          v = 0.5f * v * (1.f + tanhf(0.7978845608028654f * (v + 0.044715f * x3)));
        }
        C[(size_t)rr * N + cc] = v;
      }
    }
  }
}

// ---------------------------------------------------------------------------
// Pre-split all weights fp32 -> bf16 hi/lo into ws.  Wbil is transposed so the
// bilinear GEMM contracts over its first index.
// total 1,572,864 elems; 1536 blocks x 256 thr x 4 elems.
// ---------------------------------------------------------------------------
__global__ __launch_bounds__(256)
void prep_w(const float* __restrict__ W1, const float* __restrict__ Wa,
            const float* __restrict__ Wb, const float* __restrict__ Wc,
            const float* __restrict__ W2, const float* __restrict__ Wbil,
            const float* __restrict__ Wa1, const float* __restrict__ Wa2,
            short* __restrict__ hi, short* __restrict__ lo)
{
  int e0 = (blockIdx.x * 256 + threadIdx.x) * 4;
  const float* src; int local; bool tr = false;
  if      (e0 < 262144)  { src = W1;   local = e0; }
  else if (e0 < 393216)  { src = Wa;   local = e0 - 262144; }
  else if (e0 < 524288)  { src = Wb;   local = e0 - 393216; }
  else if (e0 < 655360)  { src = Wc;   local = e0 - 524288; }
  else if (e0 < 720896)  { src = W2;   local = e0 - 655360; }
  else if (e0 < 786432)  { src = Wbil; local = e0 - 720896; tr = true; }
  else if (e0 < 1048576) { src = Wa1;  local = e0 - 786432; }
  else                   { src = Wa2;  local = e0 - 1048576; }
  float v[4];
  if (tr) {
#pragma unroll
    for (int t = 0; t < 4; ++t) {
      int li = local + t;
      int n = li >> 8, hh = li & 255;
      v[t] = src[hh * 256 + n];        // WbilT[n][h] = Wbil[h][n]
    }
  } else {
    f32x4 tv = *reinterpret_cast<const f32x4*>(src + local);
    v[0] = tv[0]; v[1] = tv[1]; v[2] = tv[2]; v[3] = tv[3];
  }
#pragma unroll
  for (int t = 0; t < 4; ++t) {
    unsigned short h = f2bf(v[t]);
    hi[e0 + t] = (short)h;
    lo[e0 + t] = (short)f2bf(v[t] - bf2f(h));
  }
}

// ---------------------------------------------------------------------------
// RMSNorm in-place, one wave per row, 4 rows/block.
// ---------------------------------------------------------------------------
template<int L>
__global__ __launch_bounds__(256)
void rmsnorm_k(float* __restrict__ x, const float* __restrict__ g)
{
  constexpr int NV = L / 256;
  int wid = threadIdx.x >> 6, lane = threadIdx.x & 63;
  size_t row = (size_t)blockIdx.x * 4 + wid;
  float* p = x + row * L;
  f32x4 v[NV];
  float ss = 0.f;
#pragma unroll
  for (int i = 0; i < NV; ++i) {
    v[i] = *reinterpret_cast<const f32x4*>(p + (i * 64 + lane) * 4);
    ss += v[i][0] * v[i][0] + v[i][1] * v[i][1] + v[i][2] * v[i][2] + v[i][3] * v[i][3];
  }
#pragma unroll
  for (int o = 32; o > 0; o >>= 1) ss += __shfl_xor(ss, o);
  float s = rsqrtf(ss * (1.f / L) + 1e-6f);
#pragma unroll
  for (int i = 0; i < NV; ++i) {
    f32x4 gg = *reinterpret_cast<const f32x4*>(g + (i * 64 + lane) * 4);
    f32x4 o4;
#pragma unroll
    for (int j = 0; j < 4; ++j) o4[j] = v[i][j] * s * gg[j];
    *reinterpret_cast<f32x4*>(p + (i * 64 + lane) * 4) = o4;
  }
}

// t1 = silu(t1) * t2, elementwise (25,165,824 floats)
__global__ __launch_bounds__(256)
void silu_mul_k(float* __restrict__ t1, const float* __restrict__ t2)
{
  size_t i = (size_t)blockIdx.x * 256 + threadIdx.x;
  f32x4 a = reinterpret_cast<f32x4*>(t1)[i];
  f32x4 b = reinterpret_cast<const f32x4*>(t2)[i];
  f32x4 o;
#pragma unroll
  for (int j = 0; j < 4; ++j) {
    float x = a[j];
    o[j] = (x / (1.f + expf(-x))) * b[j];
  }
  reinterpret_cast<f32x4*>(t1)[i] = o;
}

// combined[r] = [mapped_src[r] (256) | tgt_enc[r] (256)]
__global__ __launch_bounds__(256)
void concat_k(const float* __restrict__ msrc, const float* __restrict__ tenc,
              float* __restrict__ comb)
{
  size_t i = (size_t)blockIdx.x * 256 + threadIdx.x;  // float4 id
  size_t r = i >> 7; int q = (int)(i & 127);
  f32x4 v;
  if (q < 64) v = reinterpret_cast<const f32x4*>(msrc)[r * 64 + q];
  else        v = reinterpret_cast<const f32x4*>(tenc)[r * 64 + (q - 64)];
  reinterpret_cast<f32x4*>(comb)[i] = v;
}

// ---------------------------------------------------------------------------
// Per-batch: scores = (P . tgtT + bbil)/TEMP, 5 sinkhorn iters, mapping=exp,
// mapped = mapping @ tgt_enc, diff/confidence.  1 wave per batch, fp32 exact.
// ---------------------------------------------------------------------------
__global__ __launch_bounds__(64)
void sinkhorn_k(const float* __restrict__ P, const float* __restrict__ Se,
                const float* __restrict__ Te, const float* __restrict__ bbil,
                const float* __restrict__ Wc1, const float* __restrict__ bc1,
                float* __restrict__ omap, float* __restrict__ omapped,
                float* __restrict__ oconf)
{
  int b = blockIdx.x, lane = threadIdx.x;
  __shared__ __attribute__((aligned(16))) float sP[6 * 260];
  __shared__ __attribute__((aligned(16))) float sT[6 * 260];
  __shared__ __attribute__((aligned(16))) float sS[6 * 260];
  const f32x4* gp = reinterpret_cast<const f32x4*>(P + (size_t)b * 1536);
  const f32x4* gt = reinterpret_cast<const f32x4*>(Te + (size_t)b * 1536);
  const f32x4* gs = reinterpret_cast<const f32x4*>(Se + (size_t)b * 1536);
#pragma unroll
  for (int i0 = 0; i0 < 6; ++i0) {
    int i = i0 * 64 + lane;
    int r = i >> 6, c = i & 63;
    *reinterpret_cast<f32x4*>(&sP[r * 260 + c * 4]) = gp[i];
    *reinterpret_cast<f32x4*>(&sT[r * 260 + c * 4]) = gt[i];
    *reinterpret_cast<f32x4*>(&sS[r * 260 + c * 4]) = gs[i];
  }
  __syncthreads();
  int i = lane / 6, j = lane - i * 6;   // valid for lane<36
  float la = 0.f;
  if (lane < 36) {
    const float* pr = &sP[i * 260];
    const float* tr = &sT[j * 260];
    float d = 0.f;
    for (int k = 0; k < 256; ++k) d = fmaf(pr[k], tr[k], d);
    la = (d + bbil[0]) * 2.0f;          // /TEMP, TEMP=0.5
  }
#pragma unroll
  for (int it = 0; it < 5; ++it) {
    float m = -1e30f, s = 0.f;
#pragma unroll
    for (int t = 0; t < 6; ++t) m = fmaxf(m, __shfl(la, i * 6 + t));
#pragma unroll
    for (int t = 0; t < 6; ++t) s += expf(__shfl(la, i * 6 + t) - m);
    la -= m + logf(s);
    m = -1e30f; s = 0.f;
#pragma unroll
    for (int t = 0; t < 6; ++t) m = fmaxf(m, __shfl(la, t * 6 + j));
#pragma unroll
    for (int t = 0; t < 6; ++t) s += expf(__shfl(la, t * 6 + j) - m);
    la -= m + logf(s);
  }
  float mp = (lane < 36) ? expf(la) : 0.f;
  if (lane < 36) omap[(size_t)b * 36 + lane] = mp;
  float mm[36];
#pragma unroll
  for (int t = 0; t < 36; ++t) mm[t] = __shfl(mp, t);
  float asum = 0.f;
#pragma unroll
  for (int ii = 0; ii < 6; ++ii) {
    f32x4 av = {0.f, 0.f, 0.f, 0.f};
#pragma unroll
    for (int k = 0; k < 6; ++k) {
      f32x4 tv = *reinterpret_cast<const f32x4*>(&sT[k * 260 + lane * 4]);
      av += tv * mm[ii * 6 + k];
    }
    f32x4 sv = *reinterpret_cast<const f32x4*>(&sS[ii * 260 + lane * 4]);
    *reinterpret_cast<f32x4*>(omapped + (size_t)b * 1536 + ii * 256 + lane * 4) = av;
    asum += fabsf(av[0] - sv[0]) + fabsf(av[1] - sv[1]) +
            fabsf(av[2] - sv[2]) + fabsf(av[3] - sv[3]);
  }
#pragma unroll
  for (int o = 32; o > 0; o >>= 1) asum += __shfl_xor(asum, o);
  if (lane == 0) {
    float ci = asum * (1.f / 1536.f);
    float z = ci * Wc1[0] + bc1[0];
    oconf[b] = 1.f / (1.f + expf(-z));
  }
}

// ---------------------------------------------------------------------------
extern "C" void kernel_launch(void* const* d_in, const int* in_sizes, int n_in,
                              void* d_out, int out_size, void* d_ws, size_t ws_size,
                              hipStream_t stream)
{
  const float* src_roles = (const float*)d_in[0];
  const float* tgt_roles = (const float*)d_in[1];
  const float* W1   = (const float*)d_in[2];
  const float* b1   = (const float*)d_in[3];
  const float* g1   = (const float*)d_in[4];
  const float* Wa   = (const float*)d_in[5];
  const float* Wb   = (const float*)d_in[6];
  const float* Wc   = (const float*)d_in[7];
  const float* W2   = (const float*)d_in[8];
  const float* b2   = (const float*)d_in[9];
  const float* Wbil = (const float*)d_in[10];
  const float* bbil = (const float*)d_in[11];
  const float* Wa1  = (const float*)d_in[12];
  const float* ba1  = (const float*)d_in[13];
  const float* Wa2  = (const float*)d_in[14];
  const float* ba2  = (const float*)d_in[15];
  const float* g2   = (const float*)d_in[16];
  const float* Wc1  = (const float*)d_in[17];
  const float* bc1  = (const float*)d_in[18];

  float* out = (float*)d_out;
  float* o_answer  = out;                  // 49152*1024
  float* o_mapping = out + 50331648;       // 8192*36
  float* o_mapped  = out + 50626560;       // 49152*256
  float* o_conf    = out + 63209472;       // 8192
  // stash in the answer region (it is written only at the very end):
  float* t1   = out;                       // 25,165,824 (swiglu gate / combined)
  float* encS = out + 25165824;            // 12,582,912
  float* encT = out + 37748736;            // 12,582,912

  float* h  = (float*)d_ws;                // 12,582,912
  float* t2 = (float*)d_ws + 12582912;     // 25,165,824 (swiglu val / P / gelu-act)
  short* whi = (short*)((float*)d_ws + 37748736);
  short* wlo = whi + 1572864;              // total ws use: ~157.3 MB

  const int oW1 = 0, oWa = 262144, oWb = 393216, oWc = 524288, oW2 = 655360,
            oWbt = 720896, oWa1 = 786432, oWa2 = 1048576;

  hipLaunchKernelGGL(prep_w, dim3(1536), dim3(256), 0, stream,
                     W1, Wa, Wb, Wc, W2, Wbil, Wa1, Wa2, whi, wlo);

  for (int s = 0; s < 2; ++s) {
    const float* X = (s == 0) ? src_roles : tgt_roles;
    float* enc = (s == 0) ? encS : encT;
    // h = X @ W1^T + b1   [49152,256], K=1024
    hipLaunchKernelGGL((gemm_nt<true, 0>), dim3(2, 384), dim3(256), 0, stream,
                       X, whi + oW1, wlo + oW1, b1, h, 1024, 256);
    hipLaunchKernelGGL((rmsnorm_k<256>), dim3(12288), dim3(256), 0, stream, h, g1);
    // swiglu
    hipLaunchKernelGGL((gemm_nt<true, 0>), dim3(4, 384), dim3(256), 0, stream,
                       h, whi + oWa, wlo + oWa, (const float*)nullptr, t1, 256, 512);
    hipLaunchKernelGGL((gemm_nt<true, 0>), dim3(4, 384), dim3(256), 0, stream,
                       h, whi + oWb, wlo + oWb, (const float*)nullptr, t2, 256, 512);
    hipLaunchKernelGGL(silu_mul_k, dim3(24576), dim3(256), 0, stream, t1, t2);
    // u = t @ Wc^T  (into h), enc = u @ W2^T + b2
    hipLaunchKernelGGL((gemm_nt<true, 0>), dim3(2, 384), dim3(256), 0, stream,
                       t1, whi + oWc, wlo + oWc, (const float*)nullptr, h, 512, 256);
    hipLaunchKernelGGL((gemm_nt<true, 0>), dim3(2, 384), dim3(256), 0, stream,
                       h, whi + oW2, wlo + oW2, b2, enc, 256, 256);
  }
  // P = encS @ Wbil  (via pre-transposed WbilT), into t2
  hipLaunchKernelGGL((gemm_nt<true, 0>), dim3(2, 384), dim3(256), 0, stream,
                     encS, whi + oWbt, wlo + oWbt, (const float*)nullptr, t2, 256, 256);
  hipLaunchKernelGGL(sinkhorn_k, dim3(8192), dim3(64), 0, stream,
                     t2, encS, encT, bbil, Wc1, bc1, o_mapping, o_mapped, o_conf);
  // combined = [mapped_src | encT] into t1 (answer region, still free)
  hipLaunchKernelGGL(concat_k, dim3(24576), dim3(256), 0, stream, o_mapped, encT, t1);
  // a = gelu(combined @ Wa1^T + ba1) into t2; answer = a @ Wa2^T + ba2; rmsnorm
  hipLaunchKernelGGL((gemm_nt<false, 1>), dim3(4, 384), dim3(256), 0, stream,
                     t1, whi + oWa1, wlo + oWa1, ba1, t2, 512, 512);
  hipLaunchKernelGGL((gemm_nt<false, 0>), dim3(8, 384), dim3(256), 0, stream,
                     t2, whi + oWa2, wlo + oWa2, ba2, o_answer, 512, 1024);
  hipLaunchKernelGGL((rmsnorm_k<1024>), dim3(12288), dim3(256), 0, stream, o_answer, g2);
}

// Round 2
// 1436.360 us; speedup vs baseline: 1.0945x; 1.0945x over previous
//
#include <hip/hip_runtime.h>
#include <hip/hip_bf16.h>

// StructureMapper: B=8192, R=6, D=1024, H=256, TEMP=0.5, 5 sinkhorn iters
// Rows = B*R = 49152. All GEMM dims are multiples of tile sizes -> no bounds checks.
//
// R2: intermediates stored as bf16 hi/lo planes (producer-side split),
//     silu*mul fused into Wb epilogue, concat fused into Wa1 A-staging,
//     answer path activations in plain bf16.

typedef float f32x4 __attribute__((ext_vector_type(4)));
typedef short s16x8 __attribute__((ext_vector_type(8)));
typedef short s16x4 __attribute__((ext_vector_type(4)));

__device__ __forceinline__ unsigned short f2bf(float x) {
  unsigned int u = __float_as_uint(x);
  u += 0x7FFFu + ((u >> 16) & 1u);            // RTNE
  return (unsigned short)(u >> 16);
}
__device__ __forceinline__ float bf2f(unsigned short b) {
  return __uint_as_float(((unsigned int)b) << 16);
}

enum { A_F32 = 0, A_PLANES = 1, A_BF16 = 2, A_CAT = 3 };
enum { E_NONE = 0, E_GELU = 1, E_SILUMUL = 2 };
enum { O_F32 = 0, O_PLANES = 1, O_BF16 = 2 };

// ---------------------------------------------------------------------------
// NT GEMM: C[m,n] = epi( sum_k A[m,k]*W[n,k] + bias[n] )
// A sources: fp32 (split on fly), bf16 hi/lo planes, plain bf16, or
//            concat(bf16 srcA[0:256) | bf16 srcB[256:512)).
// W: pre-split bf16 hi/lo [N,K]. SPLIT -> 3-pass error-compensated MFMA.
// Tile 128x128x64, 256 thr (4 waves 2x2), mfma_f32_16x16x32_bf16.
// LDS XOR swizzle: 16B chunk ch of row r lives at chunk (ch ^ (r&7)).
// ---------------------------------------------------------------------------
template<int AIN, bool SPLIT, int EPI, int OUT>
__global__ __launch_bounds__(256, 2)
void gemm2(const float* __restrict__ Af,
           const short* __restrict__ Ahi, const short* __restrict__ Alo,
           const short* __restrict__ Acat2,
           const short* __restrict__ Whi, const short* __restrict__ Wlo,
           const float* __restrict__ bias,
           float* __restrict__ Cf, short* __restrict__ Chi, short* __restrict__ Clo,
           const short* __restrict__ Xhi, const short* __restrict__ Xlo,
           int K, int N)
{
  constexpr int BM = 128, BN = 128, BK = 64;
  __shared__ __attribute__((aligned(16))) short sAhi[BM * BK];
  __shared__ __attribute__((aligned(16))) short sBhi[BN * BK];
  __shared__ __attribute__((aligned(16))) short sAlo[SPLIT ? BM * BK : 8];
  __shared__ __attribute__((aligned(16))) short sBlo[SPLIT ? BN * BK : 8];

  const int tid = threadIdx.x;
  const int n0 = blockIdx.x * BN;
  const int m0 = blockIdx.y * BM;
  const int lane = tid & 63, w = tid >> 6;
  const int wr = (w >> 1) * 64, wc = (w & 1) * 64;

  f32x4 acc[4][4] = {};

  for (int k0 = 0; k0 < K; k0 += BK) {
    __syncthreads();
    // ---- stage A ----
    if (AIN == A_F32) {
#pragma unroll
      for (int it = 0; it < 8; ++it) {
        int f = it * 256 + tid;          // float4 id within 128x64 tile
        int r = f >> 4, q = f & 15;
        f32x4 v = *reinterpret_cast<const f32x4*>(Af + (size_t)(m0 + r) * K + k0 + q * 4);
        s16x4 hi, lo;
#pragma unroll
        for (int j = 0; j < 4; ++j) {
          unsigned short h = f2bf(v[j]);
          hi[j] = (short)h;
          if (SPLIT) lo[j] = (short)f2bf(v[j] - bf2f(h));
        }
        int off = r * 64 + (((q >> 1) ^ (r & 7)) << 3) + ((q & 1) << 2);
        *reinterpret_cast<s16x4*>(&sAhi[off]) = hi;
        if (SPLIT) *reinterpret_cast<s16x4*>(&sAlo[off]) = lo;
      }
    } else {
#pragma unroll
      for (int it = 0; it < 4; ++it) {
        int c = it * 256 + tid;          // 16B-chunk id within 128x64 tile
        int r = c >> 3, ch = c & 7;
        int off = r * 64 + ((ch ^ (r & 7)) << 3);
        const short* srcHi = nullptr; const short* srcLo = nullptr;
        if (AIN == A_PLANES || AIN == A_BF16) {
          size_t g = (size_t)(m0 + r) * K + k0 + ch * 8;
          srcHi = Ahi + g;
          if (SPLIT) srcLo = Alo + g;
        } else {                          // A_CAT: [Ahi 0:256 | Acat2 256:512]
          int kk = k0 + ch * 8;
          srcHi = (kk < 256) ? (Ahi + (size_t)(m0 + r) * 256 + kk)
                             : (Acat2 + (size_t)(m0 + r) * 256 + (kk - 256));
        }
        *reinterpret_cast<s16x8*>(&sAhi[off]) = *reinterpret_cast<const s16x8*>(srcHi);
        if (SPLIT) *reinterpret_cast<s16x8*>(&sAlo[off]) = *reinterpret_cast<const s16x8*>(srcLo);
      }
    }
    // ---- stage B (pre-split weights) ----
#pragma unroll
    for (int it = 0; it < 4; ++it) {
      int c = it * 256 + tid;
      int r = c >> 3, ch = c & 7;
      size_t g = (size_t)(n0 + r) * K + k0 + ch * 8;
      int off = r * 64 + ((ch ^ (r & 7)) << 3);
      *reinterpret_cast<s16x8*>(&sBhi[off]) = *reinterpret_cast<const s16x8*>(Whi + g);
      if (SPLIT) *reinterpret_cast<s16x8*>(&sBlo[off]) = *reinterpret_cast<const s16x8*>(Wlo + g);
    }
    __syncthreads();
    // ---- MFMA ----
#pragma unroll
    for (int kc = 0; kc < 2; ++kc) {
      s16x8 ah[4], al[4];
#pragma unroll
      for (int mt = 0; mt < 4; ++mt) {
        int r = wr + mt * 16 + (lane & 15);
        int off = r * 64 + ((((kc << 2) + (lane >> 4)) ^ (r & 7)) << 3);
        ah[mt] = *reinterpret_cast<const s16x8*>(&sAhi[off]);
        if (SPLIT) al[mt] = *reinterpret_cast<const s16x8*>(&sAlo[off]);
      }
#pragma unroll
      for (int nt = 0; nt < 4; ++nt) {
        int r = wc + nt * 16 + (lane & 15);
        int off = r * 64 + ((((kc << 2) + (lane >> 4)) ^ (r & 7)) << 3);
        s16x8 bh = *reinterpret_cast<const s16x8*>(&sBhi[off]);
        s16x8 bl = {};
        if (SPLIT) bl = *reinterpret_cast<const s16x8*>(&sBlo[off]);
#pragma unroll
        for (int mt = 0; mt < 4; ++mt) {
          acc[mt][nt] = __builtin_amdgcn_mfma_f32_16x16x32_bf16(ah[mt], bh, acc[mt][nt], 0, 0, 0);
          if (SPLIT) {
            acc[mt][nt] = __builtin_amdgcn_mfma_f32_16x16x32_bf16(ah[mt], bl, acc[mt][nt], 0, 0, 0);
            acc[mt][nt] = __builtin_amdgcn_mfma_f32_16x16x32_bf16(al[mt], bh, acc[mt][nt], 0, 0, 0);
          }
        }
      }
    }
  }
  // ---- epilogue: C/D layout col=lane&15, row=(lane>>4)*4+j (m89-verified) ----
#pragma unroll
  for (int mt = 0; mt < 4; ++mt) {
#pragma unroll
    for (int nt = 0; nt < 4; ++nt) {
      int cc = n0 + wc + nt * 16 + (lane & 15);
      float bv = bias ? bias[cc] : 0.f;
#pragma unroll
      for (int j = 0; j < 4; ++j) {
        int rr = m0 + wr + mt * 16 + (lane >> 4) * 4 + j;
        float v = acc[mt][nt][j] + bv;
        size_t idx = (size_t)rr * N + cc;
        if (EPI == E_GELU) {
          float x3 = v * v * v;
          v = 0.5f * v * (1.f + tanhf(0.7978845608028654f * (v + 0.044715f * x3)));
        } else if (EPI == E_SILUMUL) {
          float xa = bf2f((unsigned short)Xhi[idx]) + bf2f((unsigned short)Xlo[idx]);
          v *= xa / (1.f + expf(-xa));
        }
        if (OUT == O_F32) {
          Cf[idx] = v;
        } else if (OUT == O_BF16) {
          Chi[idx] = (short)f2bf(v);
        } else {
          unsigned short hh = f2bf(v);
          Chi[idx] = (short)hh;
          Clo[idx] = (short)f2bf(v - bf2f(hh));
        }
      }
    }
  }
}

// ---------------------------------------------------------------------------
// Pre-split all weights fp32 -> bf16 hi/lo. Wbil pre-transposed.
// ---------------------------------------------------------------------------
__global__ __launch_bounds__(256)
void prep_w(const float* __restrict__ W1, const float* __restrict__ Wa,
            const float* __restrict__ Wb, const float* __restrict__ Wc,
            const float* __restrict__ W2, const float* __restrict__ Wbil,
            const float* __restrict__ Wa1, const float* __restrict__ Wa2,
            short* __restrict__ hi, short* __restrict__ lo)
{
  int e0 = (blockIdx.x * 256 + threadIdx.x) * 4;
  const float* src; int local; bool tr = false;
  if      (e0 < 262144)  { src = W1;   local = e0; }
  else if (e0 < 393216)  { src = Wa;   local = e0 - 262144; }
  else if (e0 < 524288)  { src = Wb;   local = e0 - 393216; }
  else if (e0 < 655360)  { src = Wc;   local = e0 - 524288; }
  else if (e0 < 720896)  { src = W2;   local = e0 - 655360; }
  else if (e0 < 786432)  { src = Wbil; local = e0 - 720896; tr = true; }
  else if (e0 < 1048576) { src = Wa1;  local = e0 - 786432; }
  else                   { src = Wa2;  local = e0 - 1048576; }
  float v[4];
  if (tr) {
#pragma unroll
    for (int t = 0; t < 4; ++t) {
      int li = local + t;
      int n = li >> 8, hh = li & 255;
      v[t] = src[hh * 256 + n];        // WbilT[n][h] = Wbil[h][n]
    }
  } else {
    f32x4 tv = *reinterpret_cast<const f32x4*>(src + local);
    v[0] = tv[0]; v[1] = tv[1]; v[2] = tv[2]; v[3] = tv[3];
  }
#pragma unroll
  for (int t = 0; t < 4; ++t) {
    unsigned short h = f2bf(v[t]);
    hi[e0 + t] = (short)h;
    lo[e0 + t] = (short)f2bf(v[t] - bf2f(h));
  }
}

// ---------------------------------------------------------------------------
// RMSNorm on hi/lo planes, L=256. One wave per row, 4 rows/block.
// ---------------------------------------------------------------------------
__global__ __launch_bounds__(256)
void rmsnorm_planes256(short* __restrict__ xhi, short* __restrict__ xlo,
                       const float* __restrict__ g)
{
  int wid = threadIdx.x >> 6, lane = threadIdx.x & 63;
  size_t row = (size_t)blockIdx.x * 4 + wid;
  short* ph = xhi + row * 256 + lane * 4;
  short* pl = xlo + row * 256 + lane * 4;
  s16x4 h4 = *reinterpret_cast<const s16x4*>(ph);
  s16x4 l4 = *reinterpret_cast<const s16x4*>(pl);
  float v[4]; float ss = 0.f;
#pragma unroll
  for (int j = 0; j < 4; ++j) {
    v[j] = bf2f((unsigned short)h4[j]) + bf2f((unsigned short)l4[j]);
    ss += v[j] * v[j];
  }
#pragma unroll
  for (int o = 32; o > 0; o >>= 1) ss += __shfl_xor(ss, o);
  float s = rsqrtf(ss * (1.f / 256.f) + 1e-6f);
  f32x4 gg = *reinterpret_cast<const f32x4*>(g + lane * 4);
#pragma unroll
  for (int j = 0; j < 4; ++j) {
    float o = v[j] * s * gg[j];
    unsigned short hh = f2bf(o);
    h4[j] = (short)hh;
    l4[j] = (short)f2bf(o - bf2f(hh));
  }
  *reinterpret_cast<s16x4*>(ph) = h4;
  *reinterpret_cast<s16x4*>(pl) = l4;
}

// ---------------------------------------------------------------------------
// RMSNorm fp32 in-place, L=1024 (answer). One wave per row, 4 rows/block.
// ---------------------------------------------------------------------------
__global__ __launch_bounds__(256)
void rmsnorm_f32_1024(float* __restrict__ x, const float* __restrict__ g)
{
  constexpr int NV = 4;
  int wid = threadIdx.x >> 6, lane = threadIdx.x & 63;
  size_t row = (size_t)blockIdx.x * 4 + wid;
  float* p = x + row * 1024;
  f32x4 v[NV];
  float ss = 0.f;
#pragma unroll
  for (int i = 0; i < NV; ++i) {
    v[i] = *reinterpret_cast<const f32x4*>(p + (i * 64 + lane) * 4);
    ss += v[i][0] * v[i][0] + v[i][1] * v[i][1] + v[i][2] * v[i][2] + v[i][3] * v[i][3];
  }
#pragma unroll
  for (int o = 32; o > 0; o >>= 1) ss += __shfl_xor(ss, o);
  float s = rsqrtf(ss * (1.f / 1024.f) + 1e-6f);
#pragma unroll
  for (int i = 0; i < NV; ++i) {
    f32x4 gg = *reinterpret_cast<const f32x4*>(g + (i * 64 + lane) * 4);
    f32x4 o4;
#pragma unroll
    for (int j = 0; j < 4; ++j) o4[j] = v[i][j] * s * gg[j];
    *reinterpret_cast<f32x4*>(p + (i * 64 + lane) * 4) = o4;
  }
}

// ---------------------------------------------------------------------------
// Per-batch sinkhorn. Enc inputs are hi/lo planes (reconstructed to fp32).
// Writes: mapping (f32 out), mapped_src (f32 out), mapped bf16 copy (ws),
// confidence (f32 out).
// ---------------------------------------------------------------------------
__global__ __launch_bounds__(64)
void sinkhorn_k(const float* __restrict__ P,
                const short* __restrict__ Sehi, const short* __restrict__ Selo,
                const short* __restrict__ Tehi, const short* __restrict__ Telo,
                const float* __restrict__ bbil,
                const float* __restrict__ Wc1, const float* __restrict__ bc1,
                float* __restrict__ omap, float* __restrict__ omapped,
                short* __restrict__ omappedb, float* __restrict__ oconf)
{
  int b = blockIdx.x, lane = threadIdx.x;
  __shared__ __attribute__((aligned(16))) float sP[6 * 260];
  __shared__ __attribute__((aligned(16))) float sT[6 * 260];
  __shared__ __attribute__((aligned(16))) float sS[6 * 260];
  const f32x4* gp = reinterpret_cast<const f32x4*>(P + (size_t)b * 1536);
#pragma unroll
  for (int i0 = 0; i0 < 6; ++i0) {
    int i = i0 * 64 + lane;
    int r = i >> 6, c = i & 63;
    *reinterpret_cast<f32x4*>(&sP[r * 260 + c * 4]) = gp[i];
    size_t e = (size_t)b * 1536 + i * 4;
    s16x4 th = *reinterpret_cast<const s16x4*>(Tehi + e);
    s16x4 tl = *reinterpret_cast<const s16x4*>(Telo + e);
    s16x4 sh = *reinterpret_cast<const s16x4*>(Sehi + e);
    s16x4 sl = *reinterpret_cast<const s16x4*>(Selo + e);
#pragma unroll
    for (int j = 0; j < 4; ++j) {
      sT[r * 260 + c * 4 + j] = bf2f((unsigned short)th[j]) + bf2f((unsigned short)tl[j]);
      sS[r * 260 + c * 4 + j] = bf2f((unsigned short)sh[j]) + bf2f((unsigned short)sl[j]);
    }
  }
  __syncthreads();
  int i = lane / 6, j = lane - i * 6;   // valid for lane<36
  float la = 0.f;
  if (lane < 36) {
    const float* pr = &sP[i * 260];
    const float* tr = &sT[j * 260];
    float d = 0.f;
    for (int k = 0; k < 256; ++k) d = fmaf(pr[k], tr[k], d);
    la = (d + bbil[0]) * 2.0f;          // /TEMP, TEMP=0.5
  }
#pragma unroll
  for (int it = 0; it < 5; ++it) {
    float m = -1e30f, s = 0.f;
#pragma unroll
    for (int t = 0; t < 6; ++t) m = fmaxf(m, __shfl(la, i * 6 + t));
#pragma unroll
    for (int t = 0; t < 6; ++t) s += expf(__shfl(la, i * 6 + t) - m);
    la -= m + logf(s);
    m = -1e30f; s = 0.f;
#pragma unroll
    for (int t = 0; t < 6; ++t) m = fmaxf(m, __shfl(la, t * 6 + j));
#pragma unroll
    for (int t = 0; t < 6; ++t) s += expf(__shfl(la, t * 6 + j) - m);
    la -= m + logf(s);
  }
  float mp = (lane < 36) ? expf(la) : 0.f;
  if (lane < 36) omap[(size_t)b * 36 + lane] = mp;
  float mm[36];
#pragma unroll
  for (int t = 0; t < 36; ++t) mm[t] = __shfl(mp, t);
  float asum = 0.f;
#pragma unroll
  for (int ii = 0; ii < 6; ++ii) {
    f32x4 av = {0.f, 0.f, 0.f, 0.f};
#pragma unroll
    for (int k = 0; k < 6; ++k) {
      f32x4 tv = *reinterpret_cast<const f32x4*>(&sT[k * 260 + lane * 4]);
      av += tv * mm[ii * 6 + k];
    }
    f32x4 sv = *reinterpret_cast<const f32x4*>(&sS[ii * 260 + lane * 4]);
    size_t e = (size_t)b * 1536 + ii * 256 + lane * 4;
    *reinterpret_cast<f32x4*>(omapped + e) = av;
    s16x4 mb;
#pragma unroll
    for (int jj = 0; jj < 4; ++jj) mb[jj] = (short)f2bf(av[jj]);
    *reinterpret_cast<s16x4*>(omappedb + e) = mb;
    asum += fabsf(av[0] - sv[0]) + fabsf(av[1] - sv[1]) +
            fabsf(av[2] - sv[2]) + fabsf(av[3] - sv[3]);
  }
#pragma unroll
  for (int o = 32; o > 0; o >>= 1) asum += __shfl_xor(asum, o);
  if (lane == 0) {
    float ci = asum * (1.f / 1536.f);
    float z = ci * Wc1[0] + bc1[0];
    oconf[b] = 1.f / (1.f + expf(-z));
  }
}

// ---------------------------------------------------------------------------
extern "C" void kernel_launch(void* const* d_in, const int* in_sizes, int n_in,
                              void* d_out, int out_size, void* d_ws, size_t ws_size,
                              hipStream_t stream)
{
  const float* src_roles = (const float*)d_in[0];
  const float* tgt_roles = (const float*)d_in[1];
  const float* W1   = (const float*)d_in[2];
  const float* b1   = (const float*)d_in[3];
  const float* g1   = (const float*)d_in[4];
  const float* Wa   = (const float*)d_in[5];
  const float* Wb   = (const float*)d_in[6];
  const float* Wc   = (const float*)d_in[7];
  const float* W2   = (const float*)d_in[8];
  const float* b2   = (const float*)d_in[9];
  const float* Wbil = (const float*)d_in[10];
  const float* bbil = (const float*)d_in[11];
  const float* Wa1  = (const float*)d_in[12];
  const float* ba1  = (const float*)d_in[13];
  const float* Wa2  = (const float*)d_in[14];
  const float* ba2  = (const float*)d_in[15];
  const float* g2   = (const float*)d_in[16];
  const float* Wc1  = (const float*)d_in[17];
  const float* bc1  = (const float*)d_in[18];

  float* out = (float*)d_out;
  float* o_answer  = out;                  // 49152*1024 f32
  float* o_mapping = out + 50331648;       // 8192*36
  float* o_mapped  = out + 50626560;       // 49152*256
  float* o_conf    = out + 63209472;       // 8192
  // stash xa / t planes in the (not-yet-written) answer region: 4 planes of
  // 25,165,824 shorts = exactly 201,326,592 B = the answer region.
  short* xa_hi = (short*)out;
  short* xa_lo = xa_hi + 25165824;
  short* t_hi  = xa_lo + 25165824;
  short* t_lo  = t_hi + 25165824;

  float* P = (float*)d_ws;                 // 12,582,912 f32
  short* sb = (short*)((float*)d_ws + 12582912);
  short* whi  = sb;                        // 1,572,864
  short* wlo  = whi + 1572864;
  short* h_hi = wlo + 1572864;             // 12,582,912 each from here on
  short* h_lo = h_hi + 12582912;
  short* u_hi = h_lo + 12582912;
  short* u_lo = u_hi + 12582912;
  short* eS_hi = u_lo + 12582912;
  short* eS_lo = eS_hi + 12582912;
  short* eT_hi = eS_lo + 12582912;
  short* eT_lo = eT_hi + 12582912;
  short* act   = eT_lo + 12582912;         // 25,165,824 (gelu out, bf16)
  short* mapb  = act + 25165824;           // 12,582,912 (mapped bf16)
  // total ws: ~333 MB

  const int oW1 = 0, oWa = 262144, oWb = 393216, oWc = 524288, oW2 = 655360,
            oWbt = 720896, oWa1 = 786432, oWa2 = 1048576;
  const short* NS = nullptr; const float* NF = nullptr;
  float* NFo = nullptr; short* NSo = nullptr;

  hipLaunchKernelGGL(prep_w, dim3(1536), dim3(256), 0, stream,
                     W1, Wa, Wb, Wc, W2, Wbil, Wa1, Wa2, whi, wlo);

  for (int s = 0; s < 2; ++s) {
    const float* X = (s == 0) ? src_roles : tgt_roles;
    short* e_hi = (s == 0) ? eS_hi : eT_hi;
    short* e_lo = (s == 0) ? eS_lo : eT_lo;
    // h = X @ W1^T + b1 -> planes   [49152,256], K=1024
    hipLaunchKernelGGL((gemm2<A_F32, true, E_NONE, O_PLANES>), dim3(2, 384), dim3(256), 0, stream,
                       X, NS, NS, NS, whi + oW1, wlo + oW1, b1, NFo, h_hi, h_lo, NS, NS, 1024, 256);
    hipLaunchKernelGGL(rmsnorm_planes256, dim3(12288), dim3(256), 0, stream, h_hi, h_lo, g1);
    // xa = h @ Wa^T -> planes       [49152,512]
    hipLaunchKernelGGL((gemm2<A_PLANES, true, E_NONE, O_PLANES>), dim3(4, 384), dim3(256), 0, stream,
                       NF, h_hi, h_lo, NS, whi + oWa, wlo + oWa, NF, NFo, xa_hi, xa_lo, NS, NS, 256, 512);
    // t = silu(xa) * (h @ Wb^T) -> planes
    hipLaunchKernelGGL((gemm2<A_PLANES, true, E_SILUMUL, O_PLANES>), dim3(4, 384), dim3(256), 0, stream,
                       NF, h_hi, h_lo, NS, whi + oWb, wlo + oWb, NF, NFo, t_hi, t_lo, xa_hi, xa_lo, 256, 512);
    // u = t @ Wc^T -> planes        [49152,256]
    hipLaunchKernelGGL((gemm2<A_PLANES, true, E_NONE, O_PLANES>), dim3(2, 384), dim3(256), 0, stream,
                       NF, t_hi, t_lo, NS, whi + oWc, wlo + oWc, NF, NFo, u_hi, u_lo, NS, NS, 512, 256);
    // enc = u @ W2^T + b2 -> planes
    hipLaunchKernelGGL((gemm2<A_PLANES, true, E_NONE, O_PLANES>), dim3(2, 384), dim3(256), 0, stream,
                       NF, u_hi, u_lo, NS, whi + oW2, wlo + oW2, b2, NFo, e_hi, e_lo, NS, NS, 256, 256);
  }
  // P = encS @ WbilT -> f32
  hipLaunchKernelGGL((gemm2<A_PLANES, true, E_NONE, O_F32>), dim3(2, 384), dim3(256), 0, stream,
                     NF, eS_hi, eS_lo, NS, whi + oWbt, wlo + oWbt, NF, P, NSo, NSo, NS, NS, 256, 256);
  hipLaunchKernelGGL(sinkhorn_k, dim3(8192), dim3(64), 0, stream,
                     P, eS_hi, eS_lo, eT_hi, eT_lo, bbil, Wc1, bc1,
                     o_mapping, o_mapped, mapb, o_conf);
  // act = gelu([mapped | encT] @ Wa1^T + ba1) -> bf16   [49152,512], K=512
  hipLaunchKernelGGL((gemm2<A_CAT, false, E_GELU, O_BF16>), dim3(4, 384), dim3(256), 0, stream,
                     NF, mapb, NS, eT_hi, whi + oWa1, wlo + oWa1, ba1, NFo, act, NSo, NS, NS, 512, 512);
  // answer = act @ Wa2^T + ba2 -> f32  [49152,1024], K=512  (overwrites stash)
  hipLaunchKernelGGL((gemm2<A_BF16, false, E_NONE, O_F32>), dim3(8, 384), dim3(256), 0, stream,
                     NF, act, NS, NS, whi + oWa2, wlo + oWa2, ba2, o_answer, NSo, NSo, NS, NS, 512, 1024);
  hipLaunchKernelGGL(rmsnorm_f32_1024, dim3(12288), dim3(256), 0, stream, o_answer, g2);
}